// Round 1
// 331.429 us; speedup vs baseline: 1.0869x; 1.0869x over previous
//
#include <hip/hip_runtime.h>
#include <math.h>

#define N_ROWS 65536
#define K_CODES 1024
#define D_DIM 256
#define TAU 0.12f

// ws layout (bytes)
#define WS_NFLAG   0        // unsigned
#define WS_CSQ     16       // float[1024]
#define WS_COUNTS  4112     // unsigned[1024]
#define WS_MINIDX  8208     // int[65536]
#define WS_LIST    270352   // int[65536]
#define WS_PART    532496   // double[256]
#define WS_CSQD    534544   // double[1024]
#define WS_CBH     542736   // _Float16[1024*256] (16B aligned)
// d_out scratch (floats):
//   xh  (f16 x, 32MB)   : [0, 8388608)
//   m1h float[2][65536] : [8388608, 8519680)
//   m2h float[2][65536] : [8519680, 8650752)
//   i1f float[2][65536] : [8650752, 8781824)
//   xsq float[65536]    : [16777218, 16842754)
// all consumed before k_out overwrites.

typedef _Float16 f16x8 __attribute__((ext_vector_type(8)));
typedef float    f32x4 __attribute__((ext_vector_type(4)));

__device__ __forceinline__ void gl_lds16(const _Float16* g, _Float16* l) {
    __builtin_amdgcn_global_load_lds(
        (const __attribute__((address_space(1))) unsigned int*)g,
        (__attribute__((address_space(3))) unsigned int*)l, 16, 0, 0);
}

// ---- prep: fp32 -> f16 for x and cb; xsq/csq(f32)/csqd(f64); zero counts/nflag
__global__ __launch_bounds__(256) void k_prep(
    const float* __restrict__ x, const float* __restrict__ cb,
    _Float16* __restrict__ xh, _Float16* __restrict__ cbh,
    float* __restrict__ xsq, float* __restrict__ csq, double* __restrict__ csqd,
    unsigned* __restrict__ counts, unsigned* __restrict__ nflag)
{
    const int b = blockIdx.x;
    const int t = threadIdx.x;
    if (b < 8192) {
        const long idx8 = (long)b * 2048 + t * 8;
        float4 v0 = *(const float4*)(x + idx8);
        float4 v1 = *(const float4*)(x + idx8 + 4);
        f16x8 h;
        h[0] = (_Float16)v0.x; h[1] = (_Float16)v0.y; h[2] = (_Float16)v0.z; h[3] = (_Float16)v0.w;
        h[4] = (_Float16)v1.x; h[5] = (_Float16)v1.y; h[6] = (_Float16)v1.z; h[7] = (_Float16)v1.w;
        *(f16x8*)(xh + idx8) = h;
        float sq = v0.x * v0.x + v0.y * v0.y + v0.z * v0.z + v0.w * v0.w
                 + v1.x * v1.x + v1.y * v1.y + v1.z * v1.z + v1.w * v1.w;
        for (int off = 16; off > 0; off >>= 1) sq += __shfl_down(sq, off, 32);
        if ((t & 31) == 0) xsq[b * 8 + (t >> 5)] = sq;
    } else {
        const int b2 = b - 8192;
        const long idx8 = (long)b2 * 2048 + t * 8;
        float4 v0 = *(const float4*)(cb + idx8);
        float4 v1 = *(const float4*)(cb + idx8 + 4);
        f16x8 h;
        h[0] = (_Float16)v0.x; h[1] = (_Float16)v0.y; h[2] = (_Float16)v0.z; h[3] = (_Float16)v0.w;
        h[4] = (_Float16)v1.x; h[5] = (_Float16)v1.y; h[6] = (_Float16)v1.z; h[7] = (_Float16)v1.w;
        *(f16x8*)(cbh + idx8) = h;
        double sqd = (double)v0.x * v0.x + (double)v0.y * v0.y
                   + (double)v0.z * v0.z + (double)v0.w * v0.w
                   + (double)v1.x * v1.x + (double)v1.y * v1.y
                   + (double)v1.z * v1.z + (double)v1.w * v1.w;
        for (int off = 16; off > 0; off >>= 1) sqd += __shfl_down(sqd, off, 32);
        if ((t & 31) == 0) {
            csqd[b2 * 8 + (t >> 5)] = sqd;
            csq[b2 * 8 + (t >> 5)] = (float)sqd;
        }
        if (b2 < 4) counts[b2 * 256 + t] = 0u;
        if (b2 == 0 && t == 0) *nflag = 0u;
    }
}

__device__ __forceinline__ void merge2(float& m1, int& i1, float& m2,
                                       float om1, int oi1, float om2) {
    float hi  = fmaxf(m1, om1);
    float lo2 = fminf(m2, om2);
    bool take = (om1 < m1) || (om1 == m1 && oi1 < i1);
    if (take) { m1 = om1; i1 = oi1; }
    m2 = fminf(hi, lo2);
}

// ---- main: 128-row x 512-code (K-half) MFMA tiles; per-row top-2 per half.
// Register footprint deliberately matches round-2's no-spill config:
// acc[16] f32x4, a[2], b[8], state 8x3. grid = 512 rowTiles x 2 halves.
__global__ __launch_bounds__(256) void k_main(
    const _Float16* __restrict__ xh, const _Float16* __restrict__ cbh,
    const float* __restrict__ csq,
    float* __restrict__ m1h, float* __restrict__ m2h, float* __restrict__ i1f)
{
    __shared__ __attribute__((aligned(16))) _Float16 As[128 * 32]; // 8 KB
    __shared__ __attribute__((aligned(16))) _Float16 Bs[128 * 32]; // 8 KB

    const int tid  = threadIdx.x;
    const int w    = tid >> 6;          // wave -> rows w*32 .. w*32+31
    const int lane = tid & 63;
    const int rlow = lane & 15;
    const int quad = lane >> 4;
    const int rowTile = blockIdx.x >> 1;
    const int half    = blockIdx.x & 1;
    const long n0  = (long)rowTile * 128;
    const int khalf = half * 512;

    float sm1[8], sm2[8];
    int   si1[8];
#pragma unroll
    for (int s = 0; s < 8; s++) { sm1[s] = INFINITY; sm2[s] = INFINITY; si1[s] = 0; }

    for (int kt = 0; kt < 4; ++kt) {
        const int kbase = khalf + kt * 128;
        f32x4 acc[16];
        const f32x4 z = {0.f, 0.f, 0.f, 0.f};
#pragma unroll
        for (int t = 0; t < 16; t++) acc[t] = z;

        for (int d0 = 0; d0 < 256; d0 += 32) {
            __syncthreads();
#pragma unroll
            for (int r = 0; r < 2; ++r) {
                int o = r * 256 + tid;          // 0..511
                gl_lds16(xh  + (n0 + (o >> 2)) * 256 + d0 + (o & 3) * 8, As + o * 8);
                gl_lds16(cbh + (long)(kbase + (o >> 2)) * 256 + d0 + (o & 3) * 8, Bs + o * 8);
            }
            __syncthreads();

            f16x8 a[2], b[8];
#pragma unroll
            for (int i = 0; i < 2; ++i)
                a[i] = *(const f16x8*)&As[(w * 32 + i * 16 + rlow) * 32 + quad * 8];
#pragma unroll
            for (int j = 0; j < 8; ++j)
                b[j] = *(const f16x8*)&Bs[(j * 16 + rlow) * 32 + quad * 8];
#pragma unroll
            for (int i = 0; i < 2; ++i)
#pragma unroll
                for (int j = 0; j < 8; ++j)
                    acc[i * 8 + j] = __builtin_amdgcn_mfma_f32_16x16x32_f16(
                        a[i], b[j], acc[i * 8 + j], 0, 0, 0);
        }

#pragma unroll
        for (int j = 0; j < 8; ++j) {
            const int code = kbase + j * 16 + rlow;
            const float csj = csq[code];
#pragma unroll
            for (int i = 0; i < 2; ++i)
#pragma unroll
                for (int v = 0; v < 4; ++v) {
                    const int s = i * 4 + v;
                    float val = fmaf(-2.f, acc[i * 8 + j][v], csj);
                    bool lt = val < sm1[s];
                    sm2[s] = fminf(fmaxf(val, sm1[s]), sm2[s]);
                    si1[s] = lt ? code : si1[s];
                    sm1[s] = fminf(val, sm1[s]);
                }
        }
    }

#pragma unroll
    for (int s = 0; s < 8; ++s) {
#pragma unroll
        for (int m = 1; m < 16; m <<= 1) {
            float om1 = __shfl_xor(sm1[s], m, 64);
            float om2 = __shfl_xor(sm2[s], m, 64);
            int   oi1 = __shfl_xor(si1[s], m, 64);
            merge2(sm1[s], si1[s], sm2[s], om1, oi1, om2);
        }
    }

    if (rlow == 0) {
        const long hb = (long)half * 65536;
#pragma unroll
        for (int i = 0; i < 2; ++i)
#pragma unroll
            for (int v = 0; v < 4; ++v) {
                const int s = i * 4 + v;
                long n = n0 + w * 32 + i * 16 + quad * 4 + v;
                m1h[hb + n] = sm1[s];
                m2h[hb + n] = sm2[s];
                i1f[hb + n] = (float)si1[s];
            }
    }
}

// ---- merge the two K-halves; flag near-ties; loss partials
__global__ __launch_bounds__(256) void k_merge(
    const float* __restrict__ m1h, const float* __restrict__ m2h,
    const float* __restrict__ i1f, const float* __restrict__ xsq,
    int* __restrict__ min_idx, int* __restrict__ list,
    unsigned* __restrict__ nflag, double* __restrict__ partials)
{
    __shared__ double red[256];
    const int tid = threadIdx.x;
    const int n = blockIdx.x * 256 + tid;

    float m1a = m1h[n], m1b = m1h[65536 + n];
    float m2a = m2h[n], m2b = m2h[65536 + n];
    int   ia  = (int)i1f[n], ib = (int)i1f[65536 + n];

    bool bw = (m1b < m1a) || (m1b == m1a && ib < ia);
    float m1 = bw ? m1b : m1a;
    int   i1 = bw ? ib : ia;
    float m2 = fminf(bw ? m1a : m1b, bw ? m2b : m2a);

    min_idx[n] = i1;
    if (m2 - m1 < TAU) { unsigned p = atomicAdd(nflag, 1u); list[p] = n; }

    red[tid] = (double)xsq[n] + (double)m1;
    __syncthreads();
    for (int off = 128; off > 0; off >>= 1) {
        if (tid < off) red[tid] += red[tid + off];
        __syncthreads();
    }
    if (tid == 0) partials[blockIdx.x] = red[0];
}

// ---- exact fp64 re-rank of flagged rows.
// Restructured for parallelism: rocprof showed the old 8-rows/block version at
// 4% occupancy (only nf/8 ~ 82 blocks active) and 4% VALUBusy, 134 us.
// Now: 2 rows/block (grid-stride), each thread owns 4 codes concurrently
// (tid, tid+256, tid+512, tid+768). Each LDS x-read and each cb fp32->fp64
// convert feeds 4 codes x 2 rows of FMAs (1:8 LDS:FMA ratio vs 1:1 before).
// dist' = csqd[k] - 2*dot (xsq row-constant -> argmin-invariant), tie-break
// on smaller k — identical math/ordering to the previous version.
#define RPB 2
__global__ __launch_bounds__(256) void k_refine(
    const float* __restrict__ x, const float* __restrict__ cb,
    const double* __restrict__ csqd, const unsigned* __restrict__ nflag,
    const int* __restrict__ list, int* __restrict__ min_idx)
{
    __shared__ double xsd[RPB][256];   // 4 KB
    __shared__ double rbv[RPB][4];
    __shared__ int    rbi[RPB][4];
    const int tid = threadIdx.x;
    const int w = tid >> 6, lane = tid & 63;
    const unsigned nf = *nflag;

    for (unsigned base = blockIdx.x * RPB; base < nf; base += gridDim.x * RPB) {
        __syncthreads();
#pragma unroll
        for (int r = 0; r < RPB; ++r) {
            unsigned it = base + r; if (it > nf - 1) it = nf - 1;
            int ridx = list[it];
            xsd[r][tid] = (double)x[(long)ridx * D_DIM + tid];   // coalesced
        }
        __syncthreads();

        const float* c0 = cb + (long)(tid)       * D_DIM;
        const float* c1 = cb + (long)(tid + 256) * D_DIM;
        const float* c2 = cb + (long)(tid + 512) * D_DIM;
        const float* c3 = cb + (long)(tid + 768) * D_DIM;

        double s0[RPB], s1[RPB], s2[RPB], s3[RPB];
#pragma unroll
        for (int r = 0; r < RPB; ++r) { s0[r] = 0.0; s1[r] = 0.0; s2[r] = 0.0; s3[r] = 0.0; }

        for (int d = 0; d < D_DIM; d += 4) {
            float4 v0 = *(const float4*)(c0 + d);
            float4 v1 = *(const float4*)(c1 + d);
            float4 v2 = *(const float4*)(c2 + d);
            float4 v3 = *(const float4*)(c3 + d);
            // convert once, reuse across RPB rows
            double a0 = (double)v0.x, a1 = (double)v0.y, a2 = (double)v0.z, a3 = (double)v0.w;
            double b0 = (double)v1.x, b1 = (double)v1.y, b2 = (double)v1.z, b3 = (double)v1.w;
            double d0 = (double)v2.x, d1 = (double)v2.y, d2 = (double)v2.z, d3 = (double)v2.w;
            double e0 = (double)v3.x, e1 = (double)v3.y, e2 = (double)v3.z, e3 = (double)v3.w;
#pragma unroll
            for (int r = 0; r < RPB; ++r) {
                double x0 = xsd[r][d], x1 = xsd[r][d + 1];
                double x2 = xsd[r][d + 2], x3 = xsd[r][d + 3];
                s0[r] = fma(x0, a0, s0[r]); s0[r] = fma(x1, a1, s0[r]);
                s0[r] = fma(x2, a2, s0[r]); s0[r] = fma(x3, a3, s0[r]);
                s1[r] = fma(x0, b0, s1[r]); s1[r] = fma(x1, b1, s1[r]);
                s1[r] = fma(x2, b2, s1[r]); s1[r] = fma(x3, b3, s1[r]);
                s2[r] = fma(x0, d0, s2[r]); s2[r] = fma(x1, d1, s2[r]);
                s2[r] = fma(x2, d2, s2[r]); s2[r] = fma(x3, d3, s2[r]);
                s3[r] = fma(x0, e0, s3[r]); s3[r] = fma(x1, e1, s3[r]);
                s3[r] = fma(x2, e2, s3[r]); s3[r] = fma(x3, e3, s3[r]);
            }
        }

        double best[RPB]; int bidx[RPB];
#pragma unroll
        for (int r = 0; r < RPB; ++r) { best[r] = 1e300; bidx[r] = 0; }
        {
            const double ck0 = csqd[tid];
            const double ck1 = csqd[tid + 256];
            const double ck2 = csqd[tid + 512];
            const double ck3 = csqd[tid + 768];
#pragma unroll
            for (int r = 0; r < RPB; ++r) {
                double dd;
                dd = fma(-2.0, s0[r], ck0);
                if (dd < best[r] || (dd == best[r] && tid < bidx[r])) { best[r] = dd; bidx[r] = tid; }
                dd = fma(-2.0, s1[r], ck1);
                if (dd < best[r] || (dd == best[r] && tid + 256 < bidx[r])) { best[r] = dd; bidx[r] = tid + 256; }
                dd = fma(-2.0, s2[r], ck2);
                if (dd < best[r] || (dd == best[r] && tid + 512 < bidx[r])) { best[r] = dd; bidx[r] = tid + 512; }
                dd = fma(-2.0, s3[r], ck3);
                if (dd < best[r] || (dd == best[r] && tid + 768 < bidx[r])) { best[r] = dd; bidx[r] = tid + 768; }
            }
        }

#pragma unroll
        for (int r = 0; r < RPB; ++r) {
            double bv = best[r]; int bi = bidx[r];
            for (int off = 32; off > 0; off >>= 1) {
                double od = __shfl_down(bv, off, 64);
                int    oi = __shfl_down(bi, off, 64);
                if (od < bv || (od == bv && oi < bi)) { bv = od; bi = oi; }
            }
            if (lane == 0) { rbv[r][w] = bv; rbi[r][w] = bi; }
        }
        __syncthreads();
        if (tid < RPB && base + tid < nf) {
            double bb = rbv[tid][0]; int bi_ = rbi[tid][0];
#pragma unroll
            for (int wv = 1; wv < 4; ++wv) {
                if (rbv[tid][wv] < bb || (rbv[tid][wv] == bb && rbi[tid][wv] < bi_)) {
                    bb = rbv[tid][wv]; bi_ = rbi[tid][wv];
                }
            }
            min_idx[list[base + tid]] = bi_;
        }
        // loop-top __syncthreads orders this read before next iter's rbv writes
    }
}

// ---- gather quantized rows, histogram, index output
__global__ __launch_bounds__(256) void k_out(
    const float* __restrict__ cb, const int* __restrict__ min_idx,
    float* __restrict__ out, unsigned* __restrict__ counts)
{
    const int tid  = threadIdx.x;
    const int wave = tid >> 6;
    const int lane = tid & 63;
    const long n = (long)blockIdx.x * 4 + wave;
    const int idx = min_idx[n];

    float4 q = *(const float4*)(cb + (long)idx * D_DIM + lane * 4);
    *(float4*)(out + n * D_DIM + lane * 4) = q;

    if (lane == 0) {
        atomicAdd(&counts[idx], 1u);
        out[16777218L + n] = (float)idx;
    }
}

__global__ void k_final(const double* __restrict__ partials,
                        const unsigned* __restrict__ counts, float* __restrict__ out)
{
    __shared__ double red[256];
    const int tid = threadIdx.x;

    red[tid] = partials[tid];
    __syncthreads();
    for (int off = 128; off > 0; off >>= 1) { if (tid < off) red[tid] += red[tid + off]; __syncthreads(); }
    double loss = red[0] / (double)((long)N_ROWS * D_DIM);
    __syncthreads();

    double h = 0.0;
    for (int k = tid; k < K_CODES; k += 256) {
        double p = (double)counts[k] / (double)N_ROWS;
        h += p * log(p + 1e-10);
    }
    red[tid] = h;
    __syncthreads();
    for (int off = 128; off > 0; off >>= 1) { if (tid < off) red[tid] += red[tid + off]; __syncthreads(); }

    if (tid == 0) {
        out[16777216] = (float)loss;
        out[16777217] = (float)exp(-red[0]);
    }
}

extern "C" void kernel_launch(void* const* d_in, const int* in_sizes, int n_in,
                              void* d_out, int out_size, void* d_ws, size_t ws_size,
                              hipStream_t stream)
{
    const float* x  = (const float*)d_in[0];
    const float* cb = (const float*)d_in[1];
    float* out = (float*)d_out;
    char*  ws  = (char*)d_ws;

    unsigned*  nflag    = (unsigned*)(ws + WS_NFLAG);
    float*     csq      = (float*)(ws + WS_CSQ);
    unsigned*  counts   = (unsigned*)(ws + WS_COUNTS);
    int*       min_idx  = (int*)(ws + WS_MINIDX);
    int*       list     = (int*)(ws + WS_LIST);
    double*    partials = (double*)(ws + WS_PART);
    double*    csqd     = (double*)(ws + WS_CSQD);
    _Float16*  cbh      = (_Float16*)(ws + WS_CBH);
    _Float16*  xh       = (_Float16*)d_out;          // floats [0, 8388608)
    float*     m1h      = out + 8388608L;
    float*     m2h      = out + 8519680L;
    float*     i1f      = out + 8650752L;
    float*     xsq      = out + 16777218L;

    hipLaunchKernelGGL(k_prep,   dim3(8192 + 128), dim3(256), 0, stream,
                       x, cb, xh, cbh, xsq, csq, csqd, counts, nflag);
    hipLaunchKernelGGL(k_main,   dim3(1024), dim3(256), 0, stream,
                       xh, cbh, csq, m1h, m2h, i1f);
    hipLaunchKernelGGL(k_merge,  dim3(256), dim3(256), 0, stream,
                       m1h, m2h, i1f, xsq, min_idx, list, nflag, partials);
    hipLaunchKernelGGL(k_refine, dim3(1024), dim3(256), 0, stream,
                       x, cb, csqd, nflag, list, min_idx);
    hipLaunchKernelGGL(k_out,    dim3(N_ROWS / 4), dim3(256), 0, stream,
                       cb, min_idx, out, counts);
    hipLaunchKernelGGL(k_final,  dim3(1), dim3(256), 0, stream, partials, counts, out);
}

// Round 2
// 263.559 us; speedup vs baseline: 1.3668x; 1.2575x over previous
//
#include <hip/hip_runtime.h>
#include <math.h>

#define N_ROWS 65536
#define K_CODES 1024
#define D_DIM 256
#define TAU 0.12f

// ws layout (bytes)
#define WS_NFLAG   0        // unsigned
#define WS_CSQ     16       // float[1024]
#define WS_COUNTS  4112     // unsigned[1024]
#define WS_MINIDX  8208     // int[65536]
#define WS_LIST    270352   // int[65536]
#define WS_PART    532496   // double[256]
#define WS_CSQD    534544   // double[1024]
#define WS_CBH     542736   // _Float16[1024*256] (16B aligned)
// d_out scratch (floats):
//   xh  (f16 x, 32MB)   : [0, 8388608)
//   m1h float[2][65536] : [8388608, 8519680)
//   m2h float[2][65536] : [8519680, 8650752)
//   i1f float[2][65536] : [8650752, 8781824)
//   cbT float[256][1024]: [8781824, 9043968)   (fp32 codebook transpose)
//   xsq float[65536]    : [16777218, 16842754)
// all consumed before k_out overwrites.

typedef _Float16 f16x8 __attribute__((ext_vector_type(8)));
typedef float    f32x4 __attribute__((ext_vector_type(4)));

__device__ __forceinline__ void gl_lds16(const _Float16* g, _Float16* l) {
    __builtin_amdgcn_global_load_lds(
        (const __attribute__((address_space(1))) unsigned int*)g,
        (__attribute__((address_space(3))) unsigned int*)l, 16, 0, 0);
}

// ---- prep: fp32 -> f16 for x and cb; xsq/csq(f32)/csqd(f64); cbT transpose;
// zero counts/nflag
__global__ __launch_bounds__(256) void k_prep(
    const float* __restrict__ x, const float* __restrict__ cb,
    _Float16* __restrict__ xh, _Float16* __restrict__ cbh,
    float* __restrict__ xsq, float* __restrict__ csq, double* __restrict__ csqd,
    float* __restrict__ cbT, unsigned* __restrict__ counts, unsigned* __restrict__ nflag)
{
    const int b = blockIdx.x;
    const int t = threadIdx.x;
    if (b < 8192) {
        const long idx8 = (long)b * 2048 + t * 8;
        float4 v0 = *(const float4*)(x + idx8);
        float4 v1 = *(const float4*)(x + idx8 + 4);
        f16x8 h;
        h[0] = (_Float16)v0.x; h[1] = (_Float16)v0.y; h[2] = (_Float16)v0.z; h[3] = (_Float16)v0.w;
        h[4] = (_Float16)v1.x; h[5] = (_Float16)v1.y; h[6] = (_Float16)v1.z; h[7] = (_Float16)v1.w;
        *(f16x8*)(xh + idx8) = h;
        float sq = v0.x * v0.x + v0.y * v0.y + v0.z * v0.z + v0.w * v0.w
                 + v1.x * v1.x + v1.y * v1.y + v1.z * v1.z + v1.w * v1.w;
        for (int off = 16; off > 0; off >>= 1) sq += __shfl_down(sq, off, 32);
        if ((t & 31) == 0) xsq[b * 8 + (t >> 5)] = sq;
    } else {
        const int b2 = b - 8192;
        const long idx8 = (long)b2 * 2048 + t * 8;
        float4 v0 = *(const float4*)(cb + idx8);
        float4 v1 = *(const float4*)(cb + idx8 + 4);
        f16x8 h;
        h[0] = (_Float16)v0.x; h[1] = (_Float16)v0.y; h[2] = (_Float16)v0.z; h[3] = (_Float16)v0.w;
        h[4] = (_Float16)v1.x; h[5] = (_Float16)v1.y; h[6] = (_Float16)v1.z; h[7] = (_Float16)v1.w;
        *(f16x8*)(cbh + idx8) = h;
        // transpose into cbT[d][k] for coalesced k_refine reads (one-time, 1 MB)
        {
            const int row = b2 * 8 + (t >> 5);      // code index
            const int col = (t & 31) * 8;           // d index base
            cbT[(col + 0) * 1024 + row] = v0.x;
            cbT[(col + 1) * 1024 + row] = v0.y;
            cbT[(col + 2) * 1024 + row] = v0.z;
            cbT[(col + 3) * 1024 + row] = v0.w;
            cbT[(col + 4) * 1024 + row] = v1.x;
            cbT[(col + 5) * 1024 + row] = v1.y;
            cbT[(col + 6) * 1024 + row] = v1.z;
            cbT[(col + 7) * 1024 + row] = v1.w;
        }
        double sqd = (double)v0.x * v0.x + (double)v0.y * v0.y
                   + (double)v0.z * v0.z + (double)v0.w * v0.w
                   + (double)v1.x * v1.x + (double)v1.y * v1.y
                   + (double)v1.z * v1.z + (double)v1.w * v1.w;
        for (int off = 16; off > 0; off >>= 1) sqd += __shfl_down(sqd, off, 32);
        if ((t & 31) == 0) {
            csqd[b2 * 8 + (t >> 5)] = sqd;
            csq[b2 * 8 + (t >> 5)] = (float)sqd;
        }
        if (b2 < 4) counts[b2 * 256 + t] = 0u;
        if (b2 == 0 && t == 0) *nflag = 0u;
    }
}

__device__ __forceinline__ void merge2(float& m1, int& i1, float& m2,
                                       float om1, int oi1, float om2) {
    float hi  = fmaxf(m1, om1);
    float lo2 = fminf(m2, om2);
    bool take = (om1 < m1) || (om1 == m1 && oi1 < i1);
    if (take) { m1 = om1; i1 = oi1; }
    m2 = fminf(hi, lo2);
}

// ---- main: 128-row x 512-code (K-half) MFMA tiles; per-row top-2 per half.
__global__ __launch_bounds__(256) void k_main(
    const _Float16* __restrict__ xh, const _Float16* __restrict__ cbh,
    const float* __restrict__ csq,
    float* __restrict__ m1h, float* __restrict__ m2h, float* __restrict__ i1f)
{
    __shared__ __attribute__((aligned(16))) _Float16 As[128 * 32]; // 8 KB
    __shared__ __attribute__((aligned(16))) _Float16 Bs[128 * 32]; // 8 KB

    const int tid  = threadIdx.x;
    const int w    = tid >> 6;          // wave -> rows w*32 .. w*32+31
    const int lane = tid & 63;
    const int rlow = lane & 15;
    const int quad = lane >> 4;
    const int rowTile = blockIdx.x >> 1;
    const int half    = blockIdx.x & 1;
    const long n0  = (long)rowTile * 128;
    const int khalf = half * 512;

    float sm1[8], sm2[8];
    int   si1[8];
#pragma unroll
    for (int s = 0; s < 8; s++) { sm1[s] = INFINITY; sm2[s] = INFINITY; si1[s] = 0; }

    for (int kt = 0; kt < 4; ++kt) {
        const int kbase = khalf + kt * 128;
        f32x4 acc[16];
        const f32x4 z = {0.f, 0.f, 0.f, 0.f};
#pragma unroll
        for (int t = 0; t < 16; t++) acc[t] = z;

        for (int d0 = 0; d0 < 256; d0 += 32) {
            __syncthreads();
#pragma unroll
            for (int r = 0; r < 2; ++r) {
                int o = r * 256 + tid;          // 0..511
                gl_lds16(xh  + (n0 + (o >> 2)) * 256 + d0 + (o & 3) * 8, As + o * 8);
                gl_lds16(cbh + (long)(kbase + (o >> 2)) * 256 + d0 + (o & 3) * 8, Bs + o * 8);
            }
            __syncthreads();

            f16x8 a[2], b[8];
#pragma unroll
            for (int i = 0; i < 2; ++i)
                a[i] = *(const f16x8*)&As[(w * 32 + i * 16 + rlow) * 32 + quad * 8];
#pragma unroll
            for (int j = 0; j < 8; ++j)
                b[j] = *(const f16x8*)&Bs[(j * 16 + rlow) * 32 + quad * 8];
#pragma unroll
            for (int i = 0; i < 2; ++i)
#pragma unroll
                for (int j = 0; j < 8; ++j)
                    acc[i * 8 + j] = __builtin_amdgcn_mfma_f32_16x16x32_f16(
                        a[i], b[j], acc[i * 8 + j], 0, 0, 0);
        }

#pragma unroll
        for (int j = 0; j < 8; ++j) {
            const int code = kbase + j * 16 + rlow;
            const float csj = csq[code];
#pragma unroll
            for (int i = 0; i < 2; ++i)
#pragma unroll
                for (int v = 0; v < 4; ++v) {
                    const int s = i * 4 + v;
                    float val = fmaf(-2.f, acc[i * 8 + j][v], csj);
                    bool lt = val < sm1[s];
                    sm2[s] = fminf(fmaxf(val, sm1[s]), sm2[s]);
                    si1[s] = lt ? code : si1[s];
                    sm1[s] = fminf(val, sm1[s]);
                }
        }
    }

#pragma unroll
    for (int s = 0; s < 8; ++s) {
#pragma unroll
        for (int m = 1; m < 16; m <<= 1) {
            float om1 = __shfl_xor(sm1[s], m, 64);
            float om2 = __shfl_xor(sm2[s], m, 64);
            int   oi1 = __shfl_xor(si1[s], m, 64);
            merge2(sm1[s], si1[s], sm2[s], om1, oi1, om2);
        }
    }

    if (rlow == 0) {
        const long hb = (long)half * 65536;
#pragma unroll
        for (int i = 0; i < 2; ++i)
#pragma unroll
            for (int v = 0; v < 4; ++v) {
                const int s = i * 4 + v;
                long n = n0 + w * 32 + i * 16 + quad * 4 + v;
                m1h[hb + n] = sm1[s];
                m2h[hb + n] = sm2[s];
                i1f[hb + n] = (float)si1[s];
            }
    }
}

// ---- merge the two K-halves; flag near-ties; loss partials
__global__ __launch_bounds__(256) void k_merge(
    const float* __restrict__ m1h, const float* __restrict__ m2h,
    const float* __restrict__ i1f, const float* __restrict__ xsq,
    int* __restrict__ min_idx, int* __restrict__ list,
    unsigned* __restrict__ nflag, double* __restrict__ partials)
{
    __shared__ double red[256];
    const int tid = threadIdx.x;
    const int n = blockIdx.x * 256 + tid;

    float m1a = m1h[n], m1b = m1h[65536 + n];
    float m2a = m2h[n], m2b = m2h[65536 + n];
    int   ia  = (int)i1f[n], ib = (int)i1f[65536 + n];

    bool bw = (m1b < m1a) || (m1b == m1a && ib < ia);
    float m1 = bw ? m1b : m1a;
    int   i1 = bw ? ib : ia;
    float m2 = fminf(bw ? m1a : m1b, bw ? m2b : m2a);

    min_idx[n] = i1;
    if (m2 - m1 < TAU) { unsigned p = atomicAdd(nflag, 1u); list[p] = n; }

    red[tid] = (double)xsq[n] + (double)m1;
    __syncthreads();
    for (int off = 128; off > 0; off >>= 1) {
        if (tid < off) red[tid] += red[tid + off];
        __syncthreads();
    }
    if (tid == 0) partials[blockIdx.x] = red[0];
}

// ---- exact fp64 re-rank of flagged rows.
// R1 rocprof: 110 us, VALUBusy 7.6%, FETCH 4.5MB -> L2-resident but
// latency-bound: per-lane cb row walks were fully uncoalesced (lanes 1KB
// apart). Now reads the fp32 codebook TRANSPOSE cbT[d][k]: thread owns codes
// 4*tid..4*tid+3, inner loop loads cbT[d][4*tid..+3] = perfectly coalesced
// float4 per lane. Same d-ascending fp64 fma chain per code -> bit-identical.
// dist' = csqd[k] - 2*dot (xsq row-constant -> argmin-invariant), tie-break
// on smaller k.
#define RPB 2
__global__ __launch_bounds__(256) void k_refine(
    const float* __restrict__ x, const float* __restrict__ cbT,
    const double* __restrict__ csqd, const unsigned* __restrict__ nflag,
    const int* __restrict__ list, int* __restrict__ min_idx)
{
    __shared__ double xsd[RPB][256];   // 4 KB
    __shared__ double rbv[RPB][4];
    __shared__ int    rbi[RPB][4];
    const int tid = threadIdx.x;
    const int w = tid >> 6, lane = tid & 63;
    const unsigned nf = *nflag;
    const int k0 = tid * 4;

    for (unsigned base = blockIdx.x * RPB; base < nf; base += gridDim.x * RPB) {
        __syncthreads();
#pragma unroll
        for (int r = 0; r < RPB; ++r) {
            unsigned it = base + r; if (it > nf - 1) it = nf - 1;
            int ridx = list[it];
            xsd[r][tid] = (double)x[(long)ridx * D_DIM + tid];   // coalesced
        }
        __syncthreads();

        double s0[RPB], s1[RPB], s2[RPB], s3[RPB];
#pragma unroll
        for (int r = 0; r < RPB; ++r) { s0[r] = 0.0; s1[r] = 0.0; s2[r] = 0.0; s3[r] = 0.0; }

#pragma unroll 4
        for (int d = 0; d < D_DIM; ++d) {
            float4 c = *(const float4*)(cbT + d * 1024 + k0);   // coalesced 16B/lane
            double c0 = (double)c.x, c1 = (double)c.y;
            double c2 = (double)c.z, c3 = (double)c.w;
#pragma unroll
            for (int r = 0; r < RPB; ++r) {
                double xv = xsd[r][d];                           // LDS broadcast
                s0[r] = fma(xv, c0, s0[r]);
                s1[r] = fma(xv, c1, s1[r]);
                s2[r] = fma(xv, c2, s2[r]);
                s3[r] = fma(xv, c3, s3[r]);
            }
        }

        double best[RPB]; int bidx[RPB];
#pragma unroll
        for (int r = 0; r < RPB; ++r) { best[r] = 1e300; bidx[r] = 0; }
        {
            const double ck0 = csqd[k0];
            const double ck1 = csqd[k0 + 1];
            const double ck2 = csqd[k0 + 2];
            const double ck3 = csqd[k0 + 3];
#pragma unroll
            for (int r = 0; r < RPB; ++r) {
                double dd;
                dd = fma(-2.0, s0[r], ck0);
                if (dd < best[r] || (dd == best[r] && k0 < bidx[r])) { best[r] = dd; bidx[r] = k0; }
                dd = fma(-2.0, s1[r], ck1);
                if (dd < best[r] || (dd == best[r] && k0 + 1 < bidx[r])) { best[r] = dd; bidx[r] = k0 + 1; }
                dd = fma(-2.0, s2[r], ck2);
                if (dd < best[r] || (dd == best[r] && k0 + 2 < bidx[r])) { best[r] = dd; bidx[r] = k0 + 2; }
                dd = fma(-2.0, s3[r], ck3);
                if (dd < best[r] || (dd == best[r] && k0 + 3 < bidx[r])) { best[r] = dd; bidx[r] = k0 + 3; }
            }
        }

#pragma unroll
        for (int r = 0; r < RPB; ++r) {
            double bv = best[r]; int bi = bidx[r];
            for (int off = 32; off > 0; off >>= 1) {
                double od = __shfl_down(bv, off, 64);
                int    oi = __shfl_down(bi, off, 64);
                if (od < bv || (od == bv && oi < bi)) { bv = od; bi = oi; }
            }
            if (lane == 0) { rbv[r][w] = bv; rbi[r][w] = bi; }
        }
        __syncthreads();
        if (tid < RPB && base + tid < nf) {
            double bb = rbv[tid][0]; int bi_ = rbi[tid][0];
#pragma unroll
            for (int wv = 1; wv < 4; ++wv) {
                if (rbv[tid][wv] < bb || (rbv[tid][wv] == bb && rbi[tid][wv] < bi_)) {
                    bb = rbv[tid][wv]; bi_ = rbi[tid][wv];
                }
            }
            min_idx[list[base + tid]] = bi_;
        }
        // loop-top __syncthreads orders this read before next iter's rbv writes
    }
}

// ---- gather quantized rows, histogram, index output
__global__ __launch_bounds__(256) void k_out(
    const float* __restrict__ cb, const int* __restrict__ min_idx,
    float* __restrict__ out, unsigned* __restrict__ counts)
{
    const int tid  = threadIdx.x;
    const int wave = tid >> 6;
    const int lane = tid & 63;
    const long n = (long)blockIdx.x * 4 + wave;
    const int idx = min_idx[n];

    float4 q = *(const float4*)(cb + (long)idx * D_DIM + lane * 4);
    *(float4*)(out + n * D_DIM + lane * 4) = q;

    if (lane == 0) {
        atomicAdd(&counts[idx], 1u);
        out[16777218L + n] = (float)idx;
    }
}

__global__ void k_final(const double* __restrict__ partials,
                        const unsigned* __restrict__ counts, float* __restrict__ out)
{
    __shared__ double red[256];
    const int tid = threadIdx.x;

    red[tid] = partials[tid];
    __syncthreads();
    for (int off = 128; off > 0; off >>= 1) { if (tid < off) red[tid] += red[tid + off]; __syncthreads(); }
    double loss = red[0] / (double)((long)N_ROWS * D_DIM);
    __syncthreads();

    double h = 0.0;
    for (int k = tid; k < K_CODES; k += 256) {
        double p = (double)counts[k] / (double)N_ROWS;
        h += p * log(p + 1e-10);
    }
    red[tid] = h;
    __syncthreads();
    for (int off = 128; off > 0; off >>= 1) { if (tid < off) red[tid] += red[tid + off]; __syncthreads(); }

    if (tid == 0) {
        out[16777216] = (float)loss;
        out[16777217] = (float)exp(-red[0]);
    }
}

extern "C" void kernel_launch(void* const* d_in, const int* in_sizes, int n_in,
                              void* d_out, int out_size, void* d_ws, size_t ws_size,
                              hipStream_t stream)
{
    const float* x  = (const float*)d_in[0];
    const float* cb = (const float*)d_in[1];
    float* out = (float*)d_out;
    char*  ws  = (char*)d_ws;

    unsigned*  nflag    = (unsigned*)(ws + WS_NFLAG);
    float*     csq      = (float*)(ws + WS_CSQ);
    unsigned*  counts   = (unsigned*)(ws + WS_COUNTS);
    int*       min_idx  = (int*)(ws + WS_MINIDX);
    int*       list     = (int*)(ws + WS_LIST);
    double*    partials = (double*)(ws + WS_PART);
    double*    csqd     = (double*)(ws + WS_CSQD);
    _Float16*  cbh      = (_Float16*)(ws + WS_CBH);
    _Float16*  xh       = (_Float16*)d_out;          // floats [0, 8388608)
    float*     m1h      = out + 8388608L;
    float*     m2h      = out + 8519680L;
    float*     i1f      = out + 8650752L;
    float*     cbT      = out + 8781824L;            // fp32 [256][1024], 1 MB
    float*     xsq      = out + 16777218L;

    hipLaunchKernelGGL(k_prep,   dim3(8192 + 128), dim3(256), 0, stream,
                       x, cb, xh, cbh, xsq, csq, csqd, cbT, counts, nflag);
    hipLaunchKernelGGL(k_main,   dim3(1024), dim3(256), 0, stream,
                       xh, cbh, csq, m1h, m2h, i1f);
    hipLaunchKernelGGL(k_merge,  dim3(256), dim3(256), 0, stream,
                       m1h, m2h, i1f, xsq, min_idx, list, nflag, partials);
    hipLaunchKernelGGL(k_refine, dim3(1024), dim3(256), 0, stream,
                       x, cbT, csqd, nflag, list, min_idx);
    hipLaunchKernelGGL(k_out,    dim3(N_ROWS / 4), dim3(256), 0, stream,
                       cb, min_idx, out, counts);
    hipLaunchKernelGGL(k_final,  dim3(1), dim3(256), 0, stream, partials, counts, out);
}

// Round 3
// 262.855 us; speedup vs baseline: 1.3705x; 1.0027x over previous
//
#include <hip/hip_runtime.h>
#include <math.h>

#define N_ROWS 65536
#define K_CODES 1024
#define D_DIM 256
#define TAU 0.12f

// ws layout (bytes)
#define WS_NFLAG   0        // unsigned
#define WS_CSQ     16       // float[1024]
#define WS_COUNTS  4112     // unsigned[1024]
#define WS_MINIDX  8208     // int[65536]
#define WS_LIST    270352   // int[65536]
#define WS_PART    532496   // double[512]
#define WS_CSQD    536592   // double[1024]
#define WS_CBH     544784   // _Float16[1024*256] (16B aligned)
// d_out scratch (floats):
//   cbT float[256][1024]: [8781824, 9043968)  (consumed by k_refine before k_out)

typedef _Float16 f16x8 __attribute__((ext_vector_type(8)));
typedef float    f32x4 __attribute__((ext_vector_type(4)));

__device__ __forceinline__ void gl_lds16(const _Float16* g, _Float16* l) {
    __builtin_amdgcn_global_load_lds(
        (const __attribute__((address_space(1))) unsigned int*)g,
        (__attribute__((address_space(3))) unsigned int*)l, 16, 0, 0);
}

// ---- prep: codebook only now (k_main converts x + computes xsq itself).
// cb -> f16 cbh; cbT fp32 transpose (for k_refine); csq f32 / csqd f64;
// zero counts/nflag.
__global__ __launch_bounds__(256) void k_prep(
    const float* __restrict__ cb, _Float16* __restrict__ cbh,
    float* __restrict__ csq, double* __restrict__ csqd,
    float* __restrict__ cbT, unsigned* __restrict__ counts,
    unsigned* __restrict__ nflag)
{
    const int b2 = blockIdx.x;
    const int t = threadIdx.x;
    const long idx8 = (long)b2 * 2048 + t * 8;
    float4 v0 = *(const float4*)(cb + idx8);
    float4 v1 = *(const float4*)(cb + idx8 + 4);
    f16x8 h;
    h[0] = (_Float16)v0.x; h[1] = (_Float16)v0.y; h[2] = (_Float16)v0.z; h[3] = (_Float16)v0.w;
    h[4] = (_Float16)v1.x; h[5] = (_Float16)v1.y; h[6] = (_Float16)v1.z; h[7] = (_Float16)v1.w;
    *(f16x8*)(cbh + idx8) = h;
    // transpose into cbT[d][k] for coalesced k_refine reads (one-time, 1 MB)
    {
        const int row = b2 * 8 + (t >> 5);      // code index
        const int col = (t & 31) * 8;           // d index base
        cbT[(col + 0) * 1024 + row] = v0.x;
        cbT[(col + 1) * 1024 + row] = v0.y;
        cbT[(col + 2) * 1024 + row] = v0.z;
        cbT[(col + 3) * 1024 + row] = v0.w;
        cbT[(col + 4) * 1024 + row] = v1.x;
        cbT[(col + 5) * 1024 + row] = v1.y;
        cbT[(col + 6) * 1024 + row] = v1.z;
        cbT[(col + 7) * 1024 + row] = v1.w;
    }
    double sqd = (double)v0.x * v0.x + (double)v0.y * v0.y
               + (double)v0.z * v0.z + (double)v0.w * v0.w
               + (double)v1.x * v1.x + (double)v1.y * v1.y
               + (double)v1.z * v1.z + (double)v1.w * v1.w;
    for (int off = 16; off > 0; off >>= 1) sqd += __shfl_down(sqd, off, 32);
    if ((t & 31) == 0) {
        csqd[b2 * 8 + (t >> 5)] = sqd;
        csq[b2 * 8 + (t >> 5)] = (float)sqd;
    }
    if (b2 < 4) counts[b2 * 256 + t] = 0u;
    if (b2 == 0 && t == 0) *nflag = 0u;
}

__device__ __forceinline__ void merge2(float& m1, int& i1, float& m2,
                                       float om1, int oi1, float om2) {
    float hi  = fmaxf(m1, om1);
    float lo2 = fminf(m2, om2);
    bool take = (om1 < m1) || (om1 == m1 && oi1 < i1);
    if (take) { m1 = om1; i1 = oi1; }
    m2 = fminf(hi, lo2);
}

// ---- main, restructured (R2 counters: 76us, MfmaUtil 18.5%, 5.2M bank-conf):
//  * 512 blocks x 128 rows; each block covers ALL 1024 codes (x read once).
//  * A-fragments in registers for all 256 dims (loaded fp32 direct from x,
//    f16 convert in-kernel = same RTN cast k_prep used). No A-LDS at all.
//  * xsq computed in-kernel, bit-identically replicating old k_prep's tree:
//    lane(rlow,q) chunk t=c*4+q; off16->c+4, off8->c+2, off4->c+1 (in-lane),
//    off2->q+2 (shfl 32), off1->q+1 (shfl 16).
//  * B double-buffered 2x16KB (BK=64), ONE barrier/phase, stage issued before
//    compute (T3-minimum pipeline), 32 MFMA per barrier.
//  * XOR swizzle slot^=row&7 on Bs (inverse pre-applied to global source) ->
//    conflict-free ds_read_b128.
//  * epilogue folds old k_merge: min_idx/list/loss partial written here.
// Per-(row,code) fp32 MFMA accumulation chain (8 asc. 32-dim chunks) is
// unchanged -> m1/m2/i1 bit-identical to the 2-half version.
__global__ __launch_bounds__(256, 2) void k_main(
    const float* __restrict__ x, const _Float16* __restrict__ cbh,
    const float* __restrict__ csq,
    int* __restrict__ min_idx, int* __restrict__ list,
    unsigned* __restrict__ nflag, double* __restrict__ partials)
{
    __shared__ __attribute__((aligned(16))) _Float16 Bs[2][128 * 64]; // 32 KB
    __shared__ float  xsq_s[128];
    __shared__ double wred[4];

    const int tid  = threadIdx.x;
    const int w    = tid >> 6;
    const int lane = tid & 63;
    const int rlow = lane & 15;
    const int quad = lane >> 4;
    const long n0  = (long)blockIdx.x * 128;

    // stage phase 0 (kt=0, d0=0..63) into Bs[0] -- overlaps A loads below
#pragma unroll
    for (int r = 0; r < 4; ++r) {
        int o = r * 256 + tid;
        int row = o >> 3, s = o & 7, g = s ^ (row & 7);
        gl_lds16(cbh + (long)row * 256 + g * 8, Bs[0] + o * 8);
    }

    // A fragments (all 256 dims) + exact xsq
    f16x8 a_reg[8][2];
#pragma unroll
    for (int i = 0; i < 2; ++i) {
        float cs[8];
        const float* rp = x + (n0 + w * 32 + i * 16 + rlow) * 256;
#pragma unroll
        for (int c = 0; c < 8; ++c) {
            const float* src = rp + c * 32 + quad * 8;
            float4 v0 = *(const float4*)src;
            float4 v1 = *(const float4*)(src + 4);
            f16x8 h;
            h[0] = (_Float16)v0.x; h[1] = (_Float16)v0.y; h[2] = (_Float16)v0.z; h[3] = (_Float16)v0.w;
            h[4] = (_Float16)v1.x; h[5] = (_Float16)v1.y; h[6] = (_Float16)v1.z; h[7] = (_Float16)v1.w;
            a_reg[c][i] = h;
            cs[c] = v0.x * v0.x + v0.y * v0.y + v0.z * v0.z + v0.w * v0.w
                  + v1.x * v1.x + v1.y * v1.y + v1.z * v1.z + v1.w * v1.w;
        }
        float s1_0 = cs[0] + cs[4], s1_1 = cs[1] + cs[5];
        float s1_2 = cs[2] + cs[6], s1_3 = cs[3] + cs[7];
        float s2_0 = s1_0 + s1_2, s2_1 = s1_1 + s1_3;
        float s3 = s2_0 + s2_1;
        float s4 = s3 + __shfl_down(s3, 32, 64);
        float s5 = s4 + __shfl_down(s4, 16, 64);
        if (quad == 0) xsq_s[w * 32 + i * 16 + rlow] = s5;
    }

    float sm1[8], sm2[8];
    int   si1[8];
#pragma unroll
    for (int s = 0; s < 8; s++) { sm1[s] = INFINITY; sm2[s] = INFINITY; si1[s] = 0; }

    f32x4 acc[16];
    const f32x4 z = {0.f, 0.f, 0.f, 0.f};
#pragma unroll
    for (int t2 = 0; t2 < 16; t2++) acc[t2] = z;

    __syncthreads();   // drains stage(0) + A loads (compiler vmcnt(0) at barrier)

    // 32 phases: kt = p>>2 (128-code tile), dblk = p&3 (64-dim block)
    for (int p = 0; p < 32; ++p) {
        const int cur = p & 1;
        if (p < 31) {   // stage next phase into other buffer (overlaps compute)
            const int pn = p + 1;
            const long kb = (long)(pn >> 2) * 128;
            const int d0 = (pn & 3) * 64;
            _Float16* dst = Bs[cur ^ 1];
#pragma unroll
            for (int r = 0; r < 4; ++r) {
                int o = r * 256 + tid;
                int row = o >> 3, s = o & 7, g = s ^ (row & 7);
                gl_lds16(cbh + (kb + row) * 256 + d0 + g * 8, dst + o * 8);
            }
        }
        const int kt = p >> 2, dblk = p & 3;
        const _Float16* B = Bs[cur];
#pragma unroll
        for (int h = 0; h < 2; ++h) {
            f16x8 b[8];
#pragma unroll
            for (int j = 0; j < 8; ++j) {
                int row = j * 16 + rlow;
                int s = (h * 4 + quad) ^ (rlow & 7);
                b[j] = *(const f16x8*)&B[row * 64 + s * 8];
            }
            const int c = dblk * 2 + h;
#pragma unroll
            for (int i = 0; i < 2; ++i)
#pragma unroll
                for (int j = 0; j < 8; ++j)
                    acc[i * 8 + j] = __builtin_amdgcn_mfma_f32_16x16x32_f16(
                        a_reg[c][i], b[j], acc[i * 8 + j], 0, 0, 0);
        }
        if (dblk == 3) {   // kt complete: top-2 update, re-zero acc
            const int kbase = kt * 128;
#pragma unroll
            for (int j = 0; j < 8; ++j) {
                const int code = kbase + j * 16 + rlow;
                const float csj = csq[code];
#pragma unroll
                for (int i = 0; i < 2; ++i)
#pragma unroll
                    for (int v = 0; v < 4; ++v) {
                        const int s = i * 4 + v;
                        float val = fmaf(-2.f, acc[i * 8 + j][v], csj);
                        bool lt = val < sm1[s];
                        sm2[s] = fminf(fmaxf(val, sm1[s]), sm2[s]);
                        si1[s] = lt ? code : si1[s];
                        sm1[s] = fminf(val, sm1[s]);
                    }
            }
#pragma unroll
            for (int t2 = 0; t2 < 16; ++t2) acc[t2] = z;
        }
        __syncthreads();
    }

    // cross-rlow top-2 merge (unchanged)
#pragma unroll
    for (int s = 0; s < 8; ++s) {
#pragma unroll
        for (int m = 1; m < 16; m <<= 1) {
            float om1 = __shfl_xor(sm1[s], m, 64);
            float om2 = __shfl_xor(sm2[s], m, 64);
            int   oi1 = __shfl_xor(si1[s], m, 64);
            merge2(sm1[s], si1[s], sm2[s], om1, oi1, om2);
        }
    }

    // epilogue = old k_merge: min_idx, near-tie flag, fp64 loss partial
    double lsum = 0.0;
    if (rlow == 0) {
#pragma unroll
        for (int i = 0; i < 2; ++i)
#pragma unroll
            for (int v = 0; v < 4; ++v) {
                const int s = i * 4 + v;
                const int rl = w * 32 + i * 16 + quad * 4 + v;
                const long n = n0 + rl;
                min_idx[n] = si1[s];
                if (sm2[s] - sm1[s] < TAU) {
                    unsigned pp = atomicAdd(nflag, 1u);
                    list[pp] = (int)n;
                }
                lsum += (double)xsq_s[rl] + (double)sm1[s];
            }
    }
    lsum += __shfl_down(lsum, 32, 64);
    lsum += __shfl_down(lsum, 16, 64);
    if (lane == 0) wred[w] = lsum;
    __syncthreads();
    if (tid == 0) partials[blockIdx.x] = ((wred[0] + wred[1]) + wred[2]) + wred[3];
}

// ---- exact fp64 re-rank of flagged rows (unchanged from R2: coalesced cbT).
#define RPB 2
__global__ __launch_bounds__(256) void k_refine(
    const float* __restrict__ x, const float* __restrict__ cbT,
    const double* __restrict__ csqd, const unsigned* __restrict__ nflag,
    const int* __restrict__ list, int* __restrict__ min_idx)
{
    __shared__ double xsd[RPB][256];   // 4 KB
    __shared__ double rbv[RPB][4];
    __shared__ int    rbi[RPB][4];
    const int tid = threadIdx.x;
    const int w = tid >> 6, lane = tid & 63;
    const unsigned nf = *nflag;
    const int k0 = tid * 4;

    for (unsigned base = blockIdx.x * RPB; base < nf; base += gridDim.x * RPB) {
        __syncthreads();
#pragma unroll
        for (int r = 0; r < RPB; ++r) {
            unsigned it = base + r; if (it > nf - 1) it = nf - 1;
            int ridx = list[it];
            xsd[r][tid] = (double)x[(long)ridx * D_DIM + tid];   // coalesced
        }
        __syncthreads();

        double s0[RPB], s1[RPB], s2[RPB], s3[RPB];
#pragma unroll
        for (int r = 0; r < RPB; ++r) { s0[r] = 0.0; s1[r] = 0.0; s2[r] = 0.0; s3[r] = 0.0; }

#pragma unroll 4
        for (int d = 0; d < D_DIM; ++d) {
            float4 c = *(const float4*)(cbT + d * 1024 + k0);   // coalesced 16B/lane
            double c0 = (double)c.x, c1 = (double)c.y;
            double c2 = (double)c.z, c3 = (double)c.w;
#pragma unroll
            for (int r = 0; r < RPB; ++r) {
                double xv = xsd[r][d];                           // LDS broadcast
                s0[r] = fma(xv, c0, s0[r]);
                s1[r] = fma(xv, c1, s1[r]);
                s2[r] = fma(xv, c2, s2[r]);
                s3[r] = fma(xv, c3, s3[r]);
            }
        }

        double best[RPB]; int bidx[RPB];
#pragma unroll
        for (int r = 0; r < RPB; ++r) { best[r] = 1e300; bidx[r] = 0; }
        {
            const double ck0 = csqd[k0];
            const double ck1 = csqd[k0 + 1];
            const double ck2 = csqd[k0 + 2];
            const double ck3 = csqd[k0 + 3];
#pragma unroll
            for (int r = 0; r < RPB; ++r) {
                double dd;
                dd = fma(-2.0, s0[r], ck0);
                if (dd < best[r] || (dd == best[r] && k0 < bidx[r])) { best[r] = dd; bidx[r] = k0; }
                dd = fma(-2.0, s1[r], ck1);
                if (dd < best[r] || (dd == best[r] && k0 + 1 < bidx[r])) { best[r] = dd; bidx[r] = k0 + 1; }
                dd = fma(-2.0, s2[r], ck2);
                if (dd < best[r] || (dd == best[r] && k0 + 2 < bidx[r])) { best[r] = dd; bidx[r] = k0 + 2; }
                dd = fma(-2.0, s3[r], ck3);
                if (dd < best[r] || (dd == best[r] && k0 + 3 < bidx[r])) { best[r] = dd; bidx[r] = k0 + 3; }
            }
        }

#pragma unroll
        for (int r = 0; r < RPB; ++r) {
            double bv = best[r]; int bi = bidx[r];
            for (int off = 32; off > 0; off >>= 1) {
                double od = __shfl_down(bv, off, 64);
                int    oi = __shfl_down(bi, off, 64);
                if (od < bv || (od == bv && oi < bi)) { bv = od; bi = oi; }
            }
            if (lane == 0) { rbv[r][w] = bv; rbi[r][w] = bi; }
        }
        __syncthreads();
        if (tid < RPB && base + tid < nf) {
            double bb = rbv[tid][0]; int bi_ = rbi[tid][0];
#pragma unroll
            for (int wv = 1; wv < 4; ++wv) {
                if (rbv[tid][wv] < bb || (rbv[tid][wv] == bb && rbi[tid][wv] < bi_)) {
                    bb = rbv[tid][wv]; bi_ = rbi[tid][wv];
                }
            }
            min_idx[list[base + tid]] = bi_;
        }
        // loop-top __syncthreads orders this read before next iter's rbv writes
    }
}

// ---- gather quantized rows, histogram, index output
__global__ __launch_bounds__(256) void k_out(
    const float* __restrict__ cb, const int* __restrict__ min_idx,
    float* __restrict__ out, unsigned* __restrict__ counts)
{
    const int tid  = threadIdx.x;
    const int wave = tid >> 6;
    const int lane = tid & 63;
    const long n = (long)blockIdx.x * 4 + wave;
    const int idx = min_idx[n];

    float4 q = *(const float4*)(cb + (long)idx * D_DIM + lane * 4);
    *(float4*)(out + n * D_DIM + lane * 4) = q;

    if (lane == 0) {
        atomicAdd(&counts[idx], 1u);
        out[16777218L + n] = (float)idx;
    }
}

__global__ void k_final(const double* __restrict__ partials,
                        const unsigned* __restrict__ counts, float* __restrict__ out)
{
    __shared__ double red[256];
    const int tid = threadIdx.x;

    red[tid] = partials[tid] + partials[tid + 256];   // 512 block partials
    __syncthreads();
    for (int off = 128; off > 0; off >>= 1) { if (tid < off) red[tid] += red[tid + off]; __syncthreads(); }
    double loss = red[0] / (double)((long)N_ROWS * D_DIM);
    __syncthreads();

    double h = 0.0;
    for (int k = tid; k < K_CODES; k += 256) {
        double p = (double)counts[k] / (double)N_ROWS;
        h += p * log(p + 1e-10);
    }
    red[tid] = h;
    __syncthreads();
    for (int off = 128; off > 0; off >>= 1) { if (tid < off) red[tid] += red[tid + off]; __syncthreads(); }

    if (tid == 0) {
        out[16777216] = (float)loss;
        out[16777217] = (float)exp(-red[0]);
    }
}

extern "C" void kernel_launch(void* const* d_in, const int* in_sizes, int n_in,
                              void* d_out, int out_size, void* d_ws, size_t ws_size,
                              hipStream_t stream)
{
    const float* x  = (const float*)d_in[0];
    const float* cb = (const float*)d_in[1];
    float* out = (float*)d_out;
    char*  ws  = (char*)d_ws;

    unsigned*  nflag    = (unsigned*)(ws + WS_NFLAG);
    float*     csq      = (float*)(ws + WS_CSQ);
    unsigned*  counts   = (unsigned*)(ws + WS_COUNTS);
    int*       min_idx  = (int*)(ws + WS_MINIDX);
    int*       list     = (int*)(ws + WS_LIST);
    double*    partials = (double*)(ws + WS_PART);
    double*    csqd     = (double*)(ws + WS_CSQD);
    _Float16*  cbh      = (_Float16*)(ws + WS_CBH);
    float*     cbT      = out + 8781824L;            // fp32 [256][1024], 1 MB

    hipLaunchKernelGGL(k_prep,   dim3(128),  dim3(256), 0, stream,
                       cb, cbh, csq, csqd, cbT, counts, nflag);
    hipLaunchKernelGGL(k_main,   dim3(512),  dim3(256), 0, stream,
                       x, cbh, csq, min_idx, list, nflag, partials);
    hipLaunchKernelGGL(k_refine, dim3(1024), dim3(256), 0, stream,
                       x, cbT, csqd, nflag, list, min_idx);
    hipLaunchKernelGGL(k_out,    dim3(N_ROWS / 4), dim3(256), 0, stream,
                       cb, min_idx, out, counts);
    hipLaunchKernelGGL(k_final,  dim3(1), dim3(256), 0, stream, partials, counts, out);
}

// Round 4
// 224.531 us; speedup vs baseline: 1.6044x; 1.1707x over previous
//
#include <hip/hip_runtime.h>
#include <math.h>

#define N_ROWS 65536
#define K_CODES 1024
#define D_DIM 256
#define TAU 0.12f

// ws layout (bytes)
#define WS_NFLAG   0        // unsigned
#define WS_CSQ     16       // float[1024]
#define WS_COUNTS  4112     // unsigned[1024]
#define WS_MINIDX  8208     // int[65536]
#define WS_LIST    270352   // int[65536]
#define WS_PART    532496   // double[512]
#define WS_CSQD    536592   // double[1024]
#define WS_CBH     544784   // _Float16[1024*256] (16B aligned)
// d_out scratch (floats):
//   cbT float[256][1024]: [8781824, 9043968)  (consumed by k_refine before k_out)

typedef _Float16 f16x8 __attribute__((ext_vector_type(8)));
typedef float    f32x4 __attribute__((ext_vector_type(4)));

__device__ __forceinline__ void gl_lds16(const _Float16* g, _Float16* l) {
    __builtin_amdgcn_global_load_lds(
        (const __attribute__((address_space(1))) unsigned int*)g,
        (__attribute__((address_space(3))) unsigned int*)l, 16, 0, 0);
}

// ---- prep: codebook only (k_main converts x + computes xsq itself).
__global__ __launch_bounds__(256) void k_prep(
    const float* __restrict__ cb, _Float16* __restrict__ cbh,
    float* __restrict__ csq, double* __restrict__ csqd,
    float* __restrict__ cbT, unsigned* __restrict__ counts,
    unsigned* __restrict__ nflag)
{
    const int b2 = blockIdx.x;
    const int t = threadIdx.x;
    const long idx8 = (long)b2 * 2048 + t * 8;
    float4 v0 = *(const float4*)(cb + idx8);
    float4 v1 = *(const float4*)(cb + idx8 + 4);
    f16x8 h;
    h[0] = (_Float16)v0.x; h[1] = (_Float16)v0.y; h[2] = (_Float16)v0.z; h[3] = (_Float16)v0.w;
    h[4] = (_Float16)v1.x; h[5] = (_Float16)v1.y; h[6] = (_Float16)v1.z; h[7] = (_Float16)v1.w;
    *(f16x8*)(cbh + idx8) = h;
    // transpose into cbT[d][k] for coalesced k_refine reads (one-time, 1 MB)
    {
        const int row = b2 * 8 + (t >> 5);      // code index
        const int col = (t & 31) * 8;           // d index base
        cbT[(col + 0) * 1024 + row] = v0.x;
        cbT[(col + 1) * 1024 + row] = v0.y;
        cbT[(col + 2) * 1024 + row] = v0.z;
        cbT[(col + 3) * 1024 + row] = v0.w;
        cbT[(col + 4) * 1024 + row] = v1.x;
        cbT[(col + 5) * 1024 + row] = v1.y;
        cbT[(col + 6) * 1024 + row] = v1.z;
        cbT[(col + 7) * 1024 + row] = v1.w;
    }
    double sqd = (double)v0.x * v0.x + (double)v0.y * v0.y
               + (double)v0.z * v0.z + (double)v0.w * v0.w
               + (double)v1.x * v1.x + (double)v1.y * v1.y
               + (double)v1.z * v1.z + (double)v1.w * v1.w;
    for (int off = 16; off > 0; off >>= 1) sqd += __shfl_down(sqd, off, 32);
    if ((t & 31) == 0) {
        csqd[b2 * 8 + (t >> 5)] = sqd;
        csq[b2 * 8 + (t >> 5)] = (float)sqd;
    }
    if (b2 < 4) counts[b2 * 256 + t] = 0u;
    if (b2 == 0 && t == 0) *nflag = 0u;
}

__device__ __forceinline__ void merge2(float& m1, int& i1, float& m2,
                                       float om1, int oi1, float om2) {
    float hi  = fmaxf(m1, om1);
    float lo2 = fminf(m2, om2);
    bool take = (om1 < m1) || (om1 == m1 && oi1 < i1);
    if (take) { m1 = om1; i1 = oi1; }
    m2 = fminf(hi, lo2);
}

// ---- main (R3 post-mortem: WRITE_SIZE 33MB = sizeof(a_reg)/thread -> a_reg
// spilled to scratch because the flat 32-phase runtime loop made
// a_reg[(p&3)*2+h] a RUNTIME index (rule #20). Fix: runtime kt (0..7) x fully
// unrolled dblk (0..3). cur = dblk&1 (kt*4 even -> phase parity == dblk
// parity, dbuf alternation identical); a_reg/acc indices now compile-time.
// Schedule, swizzle, and all arithmetic order unchanged -> bit-identical.
__global__ __launch_bounds__(256, 2) void k_main(
    const float* __restrict__ x, const _Float16* __restrict__ cbh,
    const float* __restrict__ csq,
    int* __restrict__ min_idx, int* __restrict__ list,
    unsigned* __restrict__ nflag, double* __restrict__ partials)
{
    __shared__ __attribute__((aligned(16))) _Float16 Bs[2][128 * 64]; // 32 KB
    __shared__ float  xsq_s[128];
    __shared__ double wred[4];

    const int tid  = threadIdx.x;
    const int w    = tid >> 6;
    const int lane = tid & 63;
    const int rlow = lane & 15;
    const int quad = lane >> 4;
    const long n0  = (long)blockIdx.x * 128;

    // stage phase 0 (kt=0, d0=0..63) into Bs[0] -- overlaps A loads below
#pragma unroll
    for (int r = 0; r < 4; ++r) {
        int o = r * 256 + tid;
        int row = o >> 3, s = o & 7, g = s ^ (row & 7);
        gl_lds16(cbh + (long)row * 256 + g * 8, Bs[0] + o * 8);
    }

    // A fragments (all 256 dims) + exact xsq
    f16x8 a_reg[8][2];
#pragma unroll
    for (int i = 0; i < 2; ++i) {
        float cs[8];
        const float* rp = x + (n0 + w * 32 + i * 16 + rlow) * 256;
#pragma unroll
        for (int c = 0; c < 8; ++c) {
            const float* src = rp + c * 32 + quad * 8;
            float4 v0 = *(const float4*)src;
            float4 v1 = *(const float4*)(src + 4);
            f16x8 h;
            h[0] = (_Float16)v0.x; h[1] = (_Float16)v0.y; h[2] = (_Float16)v0.z; h[3] = (_Float16)v0.w;
            h[4] = (_Float16)v1.x; h[5] = (_Float16)v1.y; h[6] = (_Float16)v1.z; h[7] = (_Float16)v1.w;
            a_reg[c][i] = h;
            cs[c] = v0.x * v0.x + v0.y * v0.y + v0.z * v0.z + v0.w * v0.w
                  + v1.x * v1.x + v1.y * v1.y + v1.z * v1.z + v1.w * v1.w;
        }
        float s1_0 = cs[0] + cs[4], s1_1 = cs[1] + cs[5];
        float s1_2 = cs[2] + cs[6], s1_3 = cs[3] + cs[7];
        float s2_0 = s1_0 + s1_2, s2_1 = s1_1 + s1_3;
        float s3 = s2_0 + s2_1;
        float s4 = s3 + __shfl_down(s3, 32, 64);
        float s5 = s4 + __shfl_down(s4, 16, 64);
        if (quad == 0) xsq_s[w * 32 + i * 16 + rlow] = s5;
    }

    float sm1[8], sm2[8];
    int   si1[8];
#pragma unroll
    for (int s = 0; s < 8; s++) { sm1[s] = INFINITY; sm2[s] = INFINITY; si1[s] = 0; }

    f32x4 acc[16];
    const f32x4 z = {0.f, 0.f, 0.f, 0.f};
#pragma unroll
    for (int t2 = 0; t2 < 16; t2++) acc[t2] = z;

    __syncthreads();   // drains stage(0) + A loads

    for (int kt = 0; kt < 8; ++kt) {
#pragma unroll
        for (int dblk = 0; dblk < 4; ++dblk) {
            const int cur = dblk & 1;            // compile-time dbuf parity
            // stage next phase into other buffer (overlaps compute)
            if (dblk != 3 || kt != 7) {
                const int  ktn = (dblk == 3) ? kt + 1 : kt;
                const int  d0  = ((dblk + 1) & 3) * 64;   // compile-time
                _Float16* dst = Bs[cur ^ 1];
#pragma unroll
                for (int r = 0; r < 4; ++r) {
                    int o = r * 256 + tid;
                    int row = o >> 3, s = o & 7, g = s ^ (row & 7);
                    gl_lds16(cbh + ((long)ktn * 128 + row) * 256 + d0 + g * 8,
                             dst + o * 8);
                }
            }
            const _Float16* B = Bs[cur];
#pragma unroll
            for (int h = 0; h < 2; ++h) {
                f16x8 b[8];
#pragma unroll
                for (int j = 0; j < 8; ++j) {
                    int row = j * 16 + rlow;
                    int s = (h * 4 + quad) ^ (rlow & 7);
                    b[j] = *(const f16x8*)&B[row * 64 + s * 8];
                }
#pragma unroll
                for (int i = 0; i < 2; ++i)
#pragma unroll
                    for (int j = 0; j < 8; ++j)
                        acc[i * 8 + j] = __builtin_amdgcn_mfma_f32_16x16x32_f16(
                            a_reg[dblk * 2 + h][i], b[j], acc[i * 8 + j], 0, 0, 0);
            }
            if (dblk == 3) {   // kt complete: top-2 update, re-zero acc
                const int kbase = kt * 128;
#pragma unroll
                for (int j = 0; j < 8; ++j) {
                    const int code = kbase + j * 16 + rlow;
                    const float csj = csq[code];
#pragma unroll
                    for (int i = 0; i < 2; ++i)
#pragma unroll
                        for (int v = 0; v < 4; ++v) {
                            const int s = i * 4 + v;
                            float val = fmaf(-2.f, acc[i * 8 + j][v], csj);
                            bool lt = val < sm1[s];
                            sm2[s] = fminf(fmaxf(val, sm1[s]), sm2[s]);
                            si1[s] = lt ? code : si1[s];
                            sm1[s] = fminf(val, sm1[s]);
                        }
                }
#pragma unroll
                for (int t2 = 0; t2 < 16; ++t2) acc[t2] = z;
            }
            __syncthreads();
        }
    }

    // cross-rlow top-2 merge (unchanged)
#pragma unroll
    for (int s = 0; s < 8; ++s) {
#pragma unroll
        for (int m = 1; m < 16; m <<= 1) {
            float om1 = __shfl_xor(sm1[s], m, 64);
            float om2 = __shfl_xor(sm2[s], m, 64);
            int   oi1 = __shfl_xor(si1[s], m, 64);
            merge2(sm1[s], si1[s], sm2[s], om1, oi1, om2);
        }
    }

    // epilogue = old k_merge: min_idx, near-tie flag, fp64 loss partial
    double lsum = 0.0;
    if (rlow == 0) {
#pragma unroll
        for (int i = 0; i < 2; ++i)
#pragma unroll
            for (int v = 0; v < 4; ++v) {
                const int s = i * 4 + v;
                const int rl = w * 32 + i * 16 + quad * 4 + v;
                const long n = n0 + rl;
                min_idx[n] = si1[s];
                if (sm2[s] - sm1[s] < TAU) {
                    unsigned pp = atomicAdd(nflag, 1u);
                    list[pp] = (int)n;
                }
                lsum += (double)xsq_s[rl] + (double)sm1[s];
            }
    }
    lsum += __shfl_down(lsum, 32, 64);
    lsum += __shfl_down(lsum, 16, 64);
    if (lane == 0) wred[w] = lsum;
    __syncthreads();
    if (tid == 0) partials[blockIdx.x] = ((wred[0] + wred[1]) + wred[2]) + wred[3];
}

// ---- exact fp64 re-rank of flagged rows (unchanged: coalesced cbT).
#define RPB 2
__global__ __launch_bounds__(256) void k_refine(
    const float* __restrict__ x, const float* __restrict__ cbT,
    const double* __restrict__ csqd, const unsigned* __restrict__ nflag,
    const int* __restrict__ list, int* __restrict__ min_idx)
{
    __shared__ double xsd[RPB][256];   // 4 KB
    __shared__ double rbv[RPB][4];
    __shared__ int    rbi[RPB][4];
    const int tid = threadIdx.x;
    const int w = tid >> 6, lane = tid & 63;
    const unsigned nf = *nflag;
    const int k0 = tid * 4;

    for (unsigned base = blockIdx.x * RPB; base < nf; base += gridDim.x * RPB) {
        __syncthreads();
#pragma unroll
        for (int r = 0; r < RPB; ++r) {
            unsigned it = base + r; if (it > nf - 1) it = nf - 1;
            int ridx = list[it];
            xsd[r][tid] = (double)x[(long)ridx * D_DIM + tid];   // coalesced
        }
        __syncthreads();

        double s0[RPB], s1[RPB], s2[RPB], s3[RPB];
#pragma unroll
        for (int r = 0; r < RPB; ++r) { s0[r] = 0.0; s1[r] = 0.0; s2[r] = 0.0; s3[r] = 0.0; }

#pragma unroll 4
        for (int d = 0; d < D_DIM; ++d) {
            float4 c = *(const float4*)(cbT + d * 1024 + k0);   // coalesced 16B/lane
            double c0 = (double)c.x, c1 = (double)c.y;
            double c2 = (double)c.z, c3 = (double)c.w;
#pragma unroll
            for (int r = 0; r < RPB; ++r) {
                double xv = xsd[r][d];                           // LDS broadcast
                s0[r] = fma(xv, c0, s0[r]);
                s1[r] = fma(xv, c1, s1[r]);
                s2[r] = fma(xv, c2, s2[r]);
                s3[r] = fma(xv, c3, s3[r]);
            }
        }

        double best[RPB]; int bidx[RPB];
#pragma unroll
        for (int r = 0; r < RPB; ++r) { best[r] = 1e300; bidx[r] = 0; }
        {
            const double ck0 = csqd[k0];
            const double ck1 = csqd[k0 + 1];
            const double ck2 = csqd[k0 + 2];
            const double ck3 = csqd[k0 + 3];
#pragma unroll
            for (int r = 0; r < RPB; ++r) {
                double dd;
                dd = fma(-2.0, s0[r], ck0);
                if (dd < best[r] || (dd == best[r] && k0 < bidx[r])) { best[r] = dd; bidx[r] = k0; }
                dd = fma(-2.0, s1[r], ck1);
                if (dd < best[r] || (dd == best[r] && k0 + 1 < bidx[r])) { best[r] = dd; bidx[r] = k0 + 1; }
                dd = fma(-2.0, s2[r], ck2);
                if (dd < best[r] || (dd == best[r] && k0 + 2 < bidx[r])) { best[r] = dd; bidx[r] = k0 + 2; }
                dd = fma(-2.0, s3[r], ck3);
                if (dd < best[r] || (dd == best[r] && k0 + 3 < bidx[r])) { best[r] = dd; bidx[r] = k0 + 3; }
            }
        }

#pragma unroll
        for (int r = 0; r < RPB; ++r) {
            double bv = best[r]; int bi = bidx[r];
            for (int off = 32; off > 0; off >>= 1) {
                double od = __shfl_down(bv, off, 64);
                int    oi = __shfl_down(bi, off, 64);
                if (od < bv || (od == bv && oi < bi)) { bv = od; bi = oi; }
            }
            if (lane == 0) { rbv[r][w] = bv; rbi[r][w] = bi; }
        }
        __syncthreads();
        if (tid < RPB && base + tid < nf) {
            double bb = rbv[tid][0]; int bi_ = rbi[tid][0];
#pragma unroll
            for (int wv = 1; wv < 4; ++wv) {
                if (rbv[tid][wv] < bb || (rbv[tid][wv] == bb && rbi[tid][wv] < bi_)) {
                    bb = rbv[tid][wv]; bi_ = rbi[tid][wv];
                }
            }
            min_idx[list[base + tid]] = bi_;
        }
        // loop-top __syncthreads orders this read before next iter's rbv writes
    }
}

// ---- gather quantized rows, histogram, index output
__global__ __launch_bounds__(256) void k_out(
    const float* __restrict__ cb, const int* __restrict__ min_idx,
    float* __restrict__ out, unsigned* __restrict__ counts)
{
    const int tid  = threadIdx.x;
    const int wave = tid >> 6;
    const int lane = tid & 63;
    const long n = (long)blockIdx.x * 4 + wave;
    const int idx = min_idx[n];

    float4 q = *(const float4*)(cb + (long)idx * D_DIM + lane * 4);
    *(float4*)(out + n * D_DIM + lane * 4) = q;

    if (lane == 0) {
        atomicAdd(&counts[idx], 1u);
        out[16777218L + n] = (float)idx;
    }
}

__global__ void k_final(const double* __restrict__ partials,
                        const unsigned* __restrict__ counts, float* __restrict__ out)
{
    __shared__ double red[256];
    const int tid = threadIdx.x;

    red[tid] = partials[tid] + partials[tid + 256];   // 512 block partials
    __syncthreads();
    for (int off = 128; off > 0; off >>= 1) { if (tid < off) red[tid] += red[tid + off]; __syncthreads(); }
    double loss = red[0] / (double)((long)N_ROWS * D_DIM);
    __syncthreads();

    double h = 0.0;
    for (int k = tid; k < K_CODES; k += 256) {
        double p = (double)counts[k] / (double)N_ROWS;
        h += p * log(p + 1e-10);
    }
    red[tid] = h;
    __syncthreads();
    for (int off = 128; off > 0; off >>= 1) { if (tid < off) red[tid] += red[tid + off]; __syncthreads(); }

    if (tid == 0) {
        out[16777216] = (float)loss;
        out[16777217] = (float)exp(-red[0]);
    }
}

extern "C" void kernel_launch(void* const* d_in, const int* in_sizes, int n_in,
                              void* d_out, int out_size, void* d_ws, size_t ws_size,
                              hipStream_t stream)
{
    const float* x  = (const float*)d_in[0];
    const float* cb = (const float*)d_in[1];
    float* out = (float*)d_out;
    char*  ws  = (char*)d_ws;

    unsigned*  nflag    = (unsigned*)(ws + WS_NFLAG);
    float*     csq      = (float*)(ws + WS_CSQ);
    unsigned*  counts   = (unsigned*)(ws + WS_COUNTS);
    int*       min_idx  = (int*)(ws + WS_MINIDX);
    int*       list     = (int*)(ws + WS_LIST);
    double*    partials = (double*)(ws + WS_PART);
    double*    csqd     = (double*)(ws + WS_CSQD);
    _Float16*  cbh      = (_Float16*)(ws + WS_CBH);
    float*     cbT      = out + 8781824L;            // fp32 [256][1024], 1 MB

    hipLaunchKernelGGL(k_prep,   dim3(128),  dim3(256), 0, stream,
                       cb, cbh, csq, csqd, cbT, counts, nflag);
    hipLaunchKernelGGL(k_main,   dim3(512),  dim3(256), 0, stream,
                       x, cbh, csq, min_idx, list, nflag, partials);
    hipLaunchKernelGGL(k_refine, dim3(1024), dim3(256), 0, stream,
                       x, cbT, csqd, nflag, list, min_idx);
    hipLaunchKernelGGL(k_out,    dim3(N_ROWS / 4), dim3(256), 0, stream,
                       cb, min_idx, out, counts);
    hipLaunchKernelGGL(k_final,  dim3(1), dim3(256), 0, stream, partials, counts, out);
}